// Round 3
// baseline (194.718 us; speedup 1.0000x reference)
//
#include <hip/hip_runtime.h>
#include <stdint.h>

// PETNNCell collapse (proven analytically):
//   T_t == 0, m == 1;  C_new = I_t + Z_c;  h = sigmoid(X @ W_h[:, :512]^T + b_h)
//   S_new = sigmoid((1 - Z_w)*S_prev + Z_w*h + X)
// Fused 4-output GEMM (Zc, Zw: K=1024 over [X,S]; It, h: K=512 over X).
//
// R3: weights pre-converted to bf16 (d_ws) -> B staged via global_load_lds
//     (double-buffered LDS, swizzle baked into the GLOBAL source address,
//     LDS dest linear = wave-uniform base + lane*16). A (X/S fp32) stays
//     reg-staged with in-kernel swizzled ds_write. One draining barrier per
//     K-step (__syncthreads); the second barrier is a raw s_barrier so the
//     kt+1 loads stay in flight across it. BN=32, 48 KiB LDS, 512 thr,
//     launch_bounds(512,6) -> 3 blocks/CU (24 waves).

#define BROWS 16384
#define DDIM  512

typedef __bf16 bf16x8 __attribute__((ext_vector_type(8)));
typedef __bf16 bf16x4 __attribute__((ext_vector_type(4)));
typedef float  f32x4  __attribute__((ext_vector_type(4)));

__device__ __forceinline__ float sigf(float x) { return 1.0f / (1.0f + __expf(-x)); }

__device__ __forceinline__ bf16x4 cvt4(f32x4 v) {
    bf16x4 r;
    r[0] = (__bf16)v[0]; r[1] = (__bf16)v[1];
    r[2] = (__bf16)v[2]; r[3] = (__bf16)v[3];
    return r;
}

__device__ __forceinline__ void glds16(const __bf16* g, __bf16* l) {
    __builtin_amdgcn_global_load_lds(
        (const __attribute__((address_space(1))) void*)g,
        (__attribute__((address_space(3))) void*)l, 16, 0, 0);
}

// ---- prepass: weights fp32 -> bf16, concatenated [Zc | Zw | Wit | Wh] ----
// elems: 512*1024, 512*1024, 512*512, 512*1024  (total 1,835,008 = 3.67 MB bf16)
__global__ __launch_bounds__(256)
void petnn_cvtw(const float* __restrict__ Wzc, const float* __restrict__ Wzw,
                const float* __restrict__ Wit, const float* __restrict__ Wh,
                __bf16* __restrict__ wb)
{
    const int i = blockIdx.x * 256 + threadIdx.x;   // f32x4 index, 458752 total
    const float* src;
    if      (i < 131072) src = Wzc + (size_t)i * 4;
    else if (i < 262144) src = Wzw + (size_t)(i - 131072) * 4;
    else if (i < 327680) src = Wit + (size_t)(i - 262144) * 4;
    else                 src = Wh  + (size_t)(i - 327680) * 4;
    *(bf16x4*)(wb + (size_t)i * 4) = cvt4(*(const f32x4*)src);
}

// Tile: BM=128 x BN=32 (per output), BK=64. 512 thr = 8 waves, 4(M) x 2(N);
// wave tile 32x16 per output. LDS: sA 16 KiB + sB dbuf 2x16 KiB = 48 KiB.
__global__ __launch_bounds__(512, 6)
void petnn_fused(const float* __restrict__ X,  const float* __restrict__ S,
                 const __bf16* __restrict__ wb,
                 const float* __restrict__ bzc, const float* __restrict__ bzw,
                 const float* __restrict__ bit_, const float* __restrict__ bh,
                 float* __restrict__ out)
{
    __shared__ __align__(16) __bf16 sA[128 * 64];
    __shared__ __align__(16) __bf16 sB[2][4 * 32 * 64];  // [buf][tile o][n][k]

    const int tid = threadIdx.x;
    const int bid = blockIdx.x;
    // XCD-chunked swizzle (2048 wgs, bijective), nblk-minor: the 16 column-
    // siblings of each mblk run consecutively on ONE XCD (A-panel L2 reuse).
    const int orig = (bid & 7) * 256 + (bid >> 3);
    const int mblk = orig >> 4;     // 0..127
    const int nblk = orig & 15;     // 0..15

    const int lane = tid & 63, wid = tid >> 6;
    const int wm = wid >> 1;        // 0..3 (32-row slice)
    const int wn = wid & 1;         // 0..1 (16-col slice)

    const int arow0 = mblk * 128;
    const int nrow0 = nblk * 32;

    // A staging (fp32 reg-staged)
    const int srow = tid >> 4;          // 0..31
    const int skq  = (tid & 15) << 2;   // float offset 0..60

    // B staging (global_load_lds, swizzle in global address).
    // Thread t owns LDS chunk t (and t+512 when full): q -> o=q>>8, n=(q>>3)&31, c=q&7.
    const int gn  = (tid >> 3) & 31;
    const int gc  = tid & 7;
    const int gcs = (gc ^ (gn & 7)) << 3;    // swizzled elem offset in 64-elem row
    const int o1  = tid >> 8;                // 0 -> Zc/Wit rounds, 1 -> Zw/Wh rounds
    const __bf16* w1 = wb + (o1 ? 524288 : 0) + (size_t)(nrow0 + gn) * 1024 + gcs;
    const __bf16* w2 = o1 ? (wb + 1310720 + (size_t)(nrow0 + gn) * 1024 + gcs)   // Wh
                          : (wb + 1048576 + (size_t)(nrow0 + gn) * 512  + gcs);  // Wit
    const int ldsq1 = (wid * 64) * 8;        // wave-uniform LDS elem base
    const int ldsq2 = 4096 + ldsq1;

    f32x4 aZc[2] = {}, aZw[2] = {}, aIt[2] = {}, aH[2] = {};
    f32x4 ra[4];

    // ---- prologue: A(0) loads first (so ds_write's vmcnt leaves glds in flight) ----
    #pragma unroll
    for (int p = 0; p < 4; ++p)
        ra[p] = *(const f32x4*)(X + (size_t)(arow0 + p * 32 + srow) * DDIM + skq);
    glds16(w1, sB[0] + ldsq1);
    glds16(w2, sB[0] + ldsq2);

    for (int kt = 0; kt < 16; ++kt) {
        const bool full = (kt < 8);

        // write A(kt) (compiler waits ra's vmcnt; glds stay in flight)
        #pragma unroll
        for (int p = 0; p < 4; ++p) {
            const int r = p * 32 + srow;
            *(bf16x4*)(sA + r * 64 + (skq ^ ((r & 7) * 8))) = cvt4(ra[p]);
        }
        __syncthreads();   // A(kt) visible; drains B(kt) glds (issued a full iter ago)

        // issue kt+1 loads: they cross the raw barrier below still in flight
        if (kt + 1 < 16) {
            const int ktn = kt + 1;
            const float* asrc = (ktn < 8) ? X : S;
            const int kga = (ktn & 7) * 64 + skq;
            #pragma unroll
            for (int p = 0; p < 4; ++p)
                ra[p] = *(const f32x4*)(asrc + (size_t)(arow0 + p * 32 + srow) * DDIM + kga);
            __bf16* bb = sB[ktn & 1];
            glds16(w1 + ktn * 64, bb + ldsq1);
            if (ktn < 8) glds16(w2 + ktn * 64, bb + ldsq2);
        }

        // ---- MFMA on sA + sB[kt&1] ----
        const __bf16* bbuf = sB[kt & 1];
        #pragma unroll
        for (int kk = 0; kk < 2; ++kk) {
            const int kbe = kk * 32 + (lane >> 4) * 8;
            bf16x8 af[2];
            #pragma unroll
            for (int mf = 0; mf < 2; ++mf) {
                const int r = wm * 32 + mf * 16 + (lane & 15);
                af[mf] = *(const bf16x8*)(sA + r * 64 + (kbe ^ ((r & 7) * 8)));
            }
            const int n  = wn * 16 + (lane & 15);
            const int sx = n * 64 + (kbe ^ ((n & 7) * 8));
            bf16x8 b0 = *(const bf16x8*)(bbuf + 0 * 2048 + sx);
            bf16x8 b1 = *(const bf16x8*)(bbuf + 1 * 2048 + sx);
            #pragma unroll
            for (int mf = 0; mf < 2; ++mf) {
                aZc[mf] = __builtin_amdgcn_mfma_f32_16x16x32_bf16(af[mf], b0, aZc[mf], 0, 0, 0);
                aZw[mf] = __builtin_amdgcn_mfma_f32_16x16x32_bf16(af[mf], b1, aZw[mf], 0, 0, 0);
            }
            if (full) {
                bf16x8 b2 = *(const bf16x8*)(bbuf + 2 * 2048 + sx);
                bf16x8 b3 = *(const bf16x8*)(bbuf + 3 * 2048 + sx);
                #pragma unroll
                for (int mf = 0; mf < 2; ++mf) {
                    aIt[mf] = __builtin_amdgcn_mfma_f32_16x16x32_bf16(af[mf], b2, aIt[mf], 0, 0, 0);
                    aH[mf]  = __builtin_amdgcn_mfma_f32_16x16x32_bf16(af[mf], b3, aH[mf], 0, 0, 0);
                }
            }
        }

        // raw (non-draining) barrier: protects sA/sB-buf reuse without
        // draining the kt+1 loads. Pinned against compiler motion.
        if (kt + 1 < 16) {
            __builtin_amdgcn_sched_barrier(0);
            asm volatile("" ::: "memory");
            __builtin_amdgcn_s_barrier();
            asm volatile("" ::: "memory");
            __builtin_amdgcn_sched_barrier(0);
        }
    }

    // ---- fused epilogue ----
    // C/D frag layout (m89/m91): col = lane&15, row = (lane>>4)*4 + reg
    const int col  = nrow0 + wn * 16 + (lane & 15);
    const int rowb = arow0 + wm * 32;
    const float vzc = bzc[col], vzw = bzw[col], vit = bit_[col], vh = bh[col];
    #pragma unroll
    for (int mf = 0; mf < 2; ++mf) {
        #pragma unroll
        for (int j = 0; j < 4; ++j) {
            const int row = rowb + mf * 16 + ((lane >> 4) << 2) + j;
            const size_t off = (size_t)row * DDIM + col;
            const float zw = sigf(aZw[mf][j] + vzw);
            const float hh = sigf(aH[mf][j] + vh);
            out[off] = sigf((1.0f - zw) * S[off] + zw * hh + X[off]);   // S_new
            out[(size_t)BROWS * DDIM + off] =
                (aZc[mf][j] + vzc) + (aIt[mf][j] + vit);                // C_new
        }
    }
}

__global__ void petnn_zeroT(float* __restrict__ t) {
    t[blockIdx.x * 256 + threadIdx.x] = 0.0f;   // T_t == 0 exactly
}

extern "C" void kernel_launch(void* const* d_in, const int* in_sizes, int n_in,
                              void* d_out, int out_size, void* d_ws, size_t ws_size,
                              hipStream_t stream) {
    (void)in_sizes; (void)n_in; (void)out_size; (void)ws_size;  // need 3.67 MB ws
    const float* X    = (const float*)d_in[0];
    const float* S    = (const float*)d_in[1];
    const float* Wzc  = (const float*)d_in[6];
    const float* bzc  = (const float*)d_in[7];
    const float* Wzw  = (const float*)d_in[8];
    const float* bzw  = (const float*)d_in[9];
    const float* Wit  = (const float*)d_in[10];
    const float* bit_ = (const float*)d_in[11];
    const float* Wh   = (const float*)d_in[14];
    const float* bh   = (const float*)d_in[15];
    float* out = (float*)d_out;
    __bf16* wb = (__bf16*)d_ws;

    petnn_cvtw<<<dim3(1792), dim3(256), 0, stream>>>(Wzc, Wzw, Wit, Wh, wb);
    petnn_fused<<<dim3(2048), dim3(512), 0, stream>>>(
        X, S, wb, bzc, bzw, bit_, bh, out);
    petnn_zeroT<<<dim3(64), dim3(256), 0, stream>>>(out + 2 * (size_t)BROWS * DDIM);
}

// Round 4
// 108.343 us; speedup vs baseline: 1.7972x; 1.7972x over previous
//
#include <hip/hip_runtime.h>
#include <stdint.h>

// PETNNCell collapse (proven analytically):
//   T_t == 0, m == 1;  C_new = I_t + Z_c;  h = sigmoid(X @ W_h[:, :512]^T + b_h)
//   S_new = sigmoid((1 - Z_w)*S_prev + Z_w*h + X)
//
// R4: family-split fused GEMM, zero vmcnt(0) drains in the K-loop.
//   fam0: P=W_Zw (K=1024 over [X,S]), Q=W_h[:, :512] (K=512) -> S_new
//   fam1: P=W_Zc (K=1024),            Q=W_It          (K=512) -> C_new
// B staged via global_load_lds (2-deep, dbuf, swizzle in global src addr);
// A (X/S f32) reg-staged 1-deep with swizzled ds_write. Barriers are raw
// s_barrier (+lgkmcnt(0) for the A write); the only vmem wait per iter is
// the compiler's counted vmcnt on ra(kt), which by in-order retirement also
// guarantees B(kt) (issued earlier) has landed - B(kt+1)/B(kt+2) stay in
// flight across both barriers.

#define BROWS 16384
#define DDIM  512

typedef __bf16 bf16x8 __attribute__((ext_vector_type(8)));
typedef __bf16 bf16x4 __attribute__((ext_vector_type(4)));
typedef float  f32x4  __attribute__((ext_vector_type(4)));

__device__ __forceinline__ float sigf(float x) { return 1.0f / (1.0f + __expf(-x)); }

__device__ __forceinline__ bf16x4 cvt4(f32x4 v) {
    bf16x4 r;
    r[0] = (__bf16)v[0]; r[1] = (__bf16)v[1];
    r[2] = (__bf16)v[2]; r[3] = (__bf16)v[3];
    return r;
}

__device__ __forceinline__ void glds16(const __bf16* g, __bf16* l) {
    __builtin_amdgcn_global_load_lds(
        (const __attribute__((address_space(1))) void*)g,
        (__attribute__((address_space(3))) void*)l, 16, 0, 0);
}

// ---- prepass: weights -> bf16 in ws, family-contiguous ----
// layout (elems): [0)      Wzw 512x1024
//                 [524288) Wh' 512x512 (cols 0..511 of W_h)
//                 [786432) Wzc 512x1024
//                 [1310720) Wit 512x512            total 1,572,864 = 3 MB
__global__ __launch_bounds__(256)
void petnn_cvtw(const float* __restrict__ Wzw, const float* __restrict__ Wh,
                const float* __restrict__ Wzc, const float* __restrict__ Wit,
                __bf16* __restrict__ wb)
{
    const int i = blockIdx.x * 256 + threadIdx.x;   // f32x4 chunk, 393216 total
    const float* src; size_t dst;
    if (i < 131072)      { src = Wzw + (size_t)i * 4;  dst = (size_t)i * 4; }
    else if (i < 196608) { const int j = i - 131072;   // Wh truncated to K=512
                           src = Wh + (size_t)(j >> 7) * 1024 + (j & 127) * 4;
                           dst = 524288 + (size_t)j * 4; }
    else if (i < 327680) { const int j = i - 196608;
                           src = Wzc + (size_t)j * 4;  dst = 786432 + (size_t)j * 4; }
    else                 { const int j = i - 327680;
                           src = Wit + (size_t)j * 4;  dst = 1310720 + (size_t)j * 4; }
    *(bf16x4*)(wb + dst) = cvt4(*(const f32x4*)src);
}

// Tile: BM=128 x BN=64, 2 outputs (P,Q), BK=64, 16 K-steps (Q only kt<8).
// 512 thr = 8 waves, 2(M) x 4(N); wave tile 64x16 per output; acc = 32 f32.
// LDS: sA[128][64] 16 KiB single + sB dbuf 2x(2x[64][64]) 32 KiB = 48 KiB.
__global__ __launch_bounds__(512, 4)
void petnn_fused(const float* __restrict__ X,   const float* __restrict__ S,
                 const __bf16* __restrict__ wb,
                 const float* __restrict__ bzw, const float* __restrict__ bh,
                 const float* __restrict__ bzc, const float* __restrict__ bit_,
                 float* __restrict__ out)
{
    __shared__ __align__(16) __bf16 sA[128 * 64];
    __shared__ __align__(16) __bf16 sB[2 * 2 * 64 * 64];  // [buf][P/Q][n][k]

    const int tid = threadIdx.x;
    const int bid = blockIdx.x;
    // XCD-chunked swizzle (2048 wgs, bijective; HW XCD = bid & 7). Each XCD
    // gets 256 consecutive orig: fam-minor, then nblk, then mblk -> the two
    // families + 8 col-blocks of an mblk co-resident on one XCD (A L2 reuse).
    const int orig = (bid & 7) * 256 + (bid >> 3);
    const int fam  = orig & 1;
    const int nblk = (orig >> 1) & 7;
    const int mblk = orig >> 4;          // 0..127

    const int lane = tid & 63, wid = tid >> 6;
    const int wm = wid >> 2;             // 0..1 (64-row half)
    const int wn = wid & 3;              // 0..3 (16-col slice)

    const int arow0 = mblk * 128;
    const int ncol0 = nblk * 64;

    // A staging (f32 reg-staged, 1-deep)
    const int srow = tid >> 4;           // 0..31
    const int skq  = (tid & 15) << 2;    // float offset 0..60

    // B staging (glds16, swizzle baked into GLOBAL source; LDS dest linear).
    // Per tile: thread t owns 16B chunk t: n = t>>3 (0..63), kc = t&7.
    const int bn  = tid >> 3;
    const int bks = ((tid & 7) ^ (bn & 7)) << 3;   // swizzled elem in 64-k row
    const __bf16* wP = wb + (size_t)fam * 786432 + (size_t)(ncol0 + bn) * 1024 + bks;
    const __bf16* wQ = wb + (size_t)fam * 786432 + 524288
                          + (size_t)(ncol0 + bn) * 512 + bks;
    __bf16* ldsB = sB + tid * 8;         // wave-uniform base + lane*16B

    f32x4 aP[4] = {}, aQ[4] = {};
    f32x4 ra[4];

    // ---- prologue: B(0), ra(0), B(1)  (B(j) older than ra(j) in vmcnt order)
    glds16(wP, ldsB);
    glds16(wQ, ldsB + 4096);
    #pragma unroll
    for (int p = 0; p < 4; ++p)
        ra[p] = *(const f32x4*)(X + (size_t)(arow0 + p * 32 + srow) * DDIM + skq);
    glds16(wP + 64, ldsB + 8192);
    glds16(wQ + 64, ldsB + 8192 + 4096);

    for (int kt = 0; kt < 16; ++kt) {
        const bool full = kt < 8;

        // cvt + write A(kt). Compiler's counted vmcnt for ra(kt) also retires
        // B(kt) (older in issue order); B(kt+1)[,B(kt+2)] remain in flight.
        #pragma unroll
        for (int p = 0; p < 4; ++p) {
            const int r = p * 32 + srow;
            *(bf16x4*)(sA + r * 64 + (skq ^ ((r & 7) * 8))) = cvt4(ra[p]);
        }

        // issue ra(kt+1) now -> a full iteration of latency cover
        if (kt + 1 < 16) {
            const float* asrc = (kt + 1 < 8) ? X : S;
            const int kga = ((kt + 1) & 7) * 64 + skq;
            #pragma unroll
            for (int p = 0; p < 4; ++p)
                ra[p] = *(const f32x4*)(asrc + (size_t)(arow0 + p * 32 + srow) * DDIM + kga);
        }

        // barrier-1: A(kt) ds_writes visible; NO vmcnt drain
        asm volatile("s_waitcnt lgkmcnt(0)" ::: "memory");
        __builtin_amdgcn_s_barrier();

        // ---- MFMA on sA + sB[kt&1] ----
        const __bf16* bb = sB + (kt & 1) * 8192;
        #pragma unroll
        for (int kk = 0; kk < 2; ++kk) {
            const int kbe = kk * 32 + (lane >> 4) * 8;
            bf16x8 af[4];
            #pragma unroll
            for (int mf = 0; mf < 4; ++mf) {
                const int r = wm * 64 + mf * 16 + (lane & 15);
                af[mf] = *(const bf16x8*)(sA + r * 64 + (kbe ^ ((r & 7) * 8)));
            }
            const int nr = wn * 16 + (lane & 15);
            const int sx = nr * 64 + (kbe ^ ((nr & 7) * 8));
            const bf16x8 bP = *(const bf16x8*)(bb + sx);
            #pragma unroll
            for (int mf = 0; mf < 4; ++mf)
                aP[mf] = __builtin_amdgcn_mfma_f32_16x16x32_bf16(af[mf], bP, aP[mf], 0, 0, 0);
            if (full) {
                const bf16x8 bQ = *(const bf16x8*)(bb + 4096 + sx);
                #pragma unroll
                for (int mf = 0; mf < 4; ++mf)
                    aQ[mf] = __builtin_amdgcn_mfma_f32_16x16x32_bf16(af[mf], bQ, aQ[mf], 0, 0, 0);
            }
        }

        if (kt + 1 < 16) {
            // barrier-2 (raw): all waves done reading sA and sB[kt&1];
            // in-flight loads are NOT drained here.
            asm volatile("" ::: "memory");
            __builtin_amdgcn_s_barrier();
            asm volatile("" ::: "memory");
            // issue B(kt+2) into the just-freed buffer (2-deep pipeline)
            if (kt + 2 < 16) {
                __bf16* bd = sB + (kt & 1) * 8192 + tid * 8;
                glds16(wP + (size_t)(kt + 2) * 64, bd);
                if (kt + 2 < 8) glds16(wQ + (size_t)(kt + 2) * 64, bd + 4096);
            }
        }
    }

    // ---- fused epilogue ----
    // C/D frag layout (m89/m91): col = lane&15, row = (lane>>4)*4 + reg
    const int col  = ncol0 + wn * 16 + (lane & 15);
    const int rowb = arow0 + wm * 64;
    if (fam == 0) {
        const float vzw = bzw[col], vh = bh[col];
        #pragma unroll
        for (int mf = 0; mf < 4; ++mf) {
            #pragma unroll
            for (int j = 0; j < 4; ++j) {
                const int row = rowb + mf * 16 + ((lane >> 4) << 2) + j;
                const size_t off = (size_t)row * DDIM + col;
                const float zw = sigf(aP[mf][j] + vzw);
                const float hh = sigf(aQ[mf][j] + vh);
                out[off] = sigf((1.0f - zw) * S[off] + zw * hh + X[off]);  // S_new
            }
        }
    } else {
        const float vzc = bzc[col], vit = bit_[col];
        #pragma unroll
        for (int mf = 0; mf < 4; ++mf) {
            #pragma unroll
            for (int j = 0; j < 4; ++j) {
                const int row = rowb + mf * 16 + ((lane >> 4) << 2) + j;
                const size_t off = (size_t)row * DDIM + col;
                out[(size_t)BROWS * DDIM + off] =
                    (aP[mf][j] + vzc) + (aQ[mf][j] + vit);                 // C_new
            }
        }
    }
}

__global__ void petnn_zeroT(float* __restrict__ t) {
    t[blockIdx.x * 256 + threadIdx.x] = 0.0f;   // T_t == 0 exactly
}

extern "C" void kernel_launch(void* const* d_in, const int* in_sizes, int n_in,
                              void* d_out, int out_size, void* d_ws, size_t ws_size,
                              hipStream_t stream) {
    (void)in_sizes; (void)n_in; (void)out_size; (void)ws_size;  // ws: 3 MB used
    const float* X    = (const float*)d_in[0];
    const float* S    = (const float*)d_in[1];
    const float* Wzc  = (const float*)d_in[6];
    const float* bzc  = (const float*)d_in[7];
    const float* Wzw  = (const float*)d_in[8];
    const float* bzw  = (const float*)d_in[9];
    const float* Wit  = (const float*)d_in[10];
    const float* bit_ = (const float*)d_in[11];
    const float* Wh   = (const float*)d_in[14];
    const float* bh   = (const float*)d_in[15];
    float* out = (float*)d_out;
    __bf16* wb = (__bf16*)d_ws;

    petnn_cvtw<<<dim3(1536), dim3(256), 0, stream>>>(Wzw, Wh, Wzc, Wit, wb);
    petnn_fused<<<dim3(2048), dim3(512), 0, stream>>>(
        X, S, wb, bzw, bh, bzc, bit_, out);
    petnn_zeroT<<<dim3(64), dim3(256), 0, stream>>>(out + 2 * (size_t)BROWS * DDIM);
}

// Round 5
// 100.684 us; speedup vs baseline: 1.9339x; 1.0761x over previous
//
#include <hip/hip_runtime.h>
#include <stdint.h>

// PETNNCell collapse (proven analytically):
//   T_t == 0, m == 1;  C_new = I_t + Z_c;  h = sigmoid(X @ W_h[:, :512]^T + b_h)
//   S_new = sigmoid((1 - Z_w)*S_prev + Z_w*h + X)
//
// R5: all-bf16 prepass (X, S, weights -> d_ws), then a pure-async main loop:
// A and B both staged by global_load_lds, 2-deep double-buffered, XOR-swizzle
// baked into the GLOBAL source address (LDS dest linear). Per K-step the only
// vmem wait is a counted vmcnt(4/3): tile kt's loads were issued 2 iterations
// earlier; kt+1 / kt+2 loads stay in flight across both raw s_barriers.
// Zero staging VALU in the K-loop. Family split: fam0 {Zw,h}->S_new,
// fam1 {Zc,It}->C_new. Fallback to the R4 reg-staged path if ws too small.

#define BROWS 16384
#define DDIM  512

typedef __bf16 bf16x8 __attribute__((ext_vector_type(8)));
typedef __bf16 bf16x4 __attribute__((ext_vector_type(4)));
typedef float  f32x4  __attribute__((ext_vector_type(4)));

__device__ __forceinline__ float sigf(float x) { return 1.0f / (1.0f + __expf(-x)); }

__device__ __forceinline__ bf16x4 cvt4(f32x4 v) {
    bf16x4 r;
    r[0] = (__bf16)v[0]; r[1] = (__bf16)v[1];
    r[2] = (__bf16)v[2]; r[3] = (__bf16)v[3];
    return r;
}

__device__ __forceinline__ void glds16(const __bf16* g, __bf16* l) {
    __builtin_amdgcn_global_load_lds(
        (const __attribute__((address_space(1))) void*)g,
        (__attribute__((address_space(3))) void*)l, 16, 0, 0);
}

template<int N> __device__ __forceinline__ void waitvm();
template<> __device__ __forceinline__ void waitvm<0>() { asm volatile("s_waitcnt vmcnt(0)" ::: "memory"); }
template<> __device__ __forceinline__ void waitvm<3>() { asm volatile("s_waitcnt vmcnt(3)" ::: "memory"); }
template<> __device__ __forceinline__ void waitvm<4>() { asm volatile("s_waitcnt vmcnt(4)" ::: "memory"); }

// ===================== R5 prepass: X, S, weights -> bf16 =====================
// ws elems: [0) Xb 8388608 | [8388608) Sb 8388608 | [16777216) weights:
//   +0 Wzw 512x1024 | +524288 Wh' 512x512 | +786432 Wzc 512x1024 | +1310720 Wit 512x512
__global__ __launch_bounds__(256)
void petnn_cvt(const float* __restrict__ X,   const float* __restrict__ S,
               const float* __restrict__ Wzw, const float* __restrict__ Wh,
               const float* __restrict__ Wzc, const float* __restrict__ Wit,
               __bf16* __restrict__ ws)
{
    const int i = blockIdx.x * 256 + threadIdx.x;   // f32x4 chunk, 4587520 total
    const float* src; size_t dst;
    if (i < 2097152)      { src = X + (size_t)i * 4; dst = (size_t)i * 4; }
    else if (i < 4194304) { const int j = i - 2097152;
                            src = S + (size_t)j * 4; dst = 8388608 + (size_t)j * 4; }
    else {
        const int j = i - 4194304;                  // 0..393215 (weights)
        if (j < 131072)      { src = Wzw + (size_t)j * 4;
                               dst = 16777216 + (size_t)j * 4; }
        else if (j < 196608) { const int jj = j - 131072;   // Wh cols 0..511
                               src = Wh + (size_t)(jj >> 7) * 1024 + (jj & 127) * 4;
                               dst = 16777216 + 524288 + (size_t)jj * 4; }
        else if (j < 327680) { const int jj = j - 196608;
                               src = Wzc + (size_t)jj * 4;
                               dst = 16777216 + 786432 + (size_t)jj * 4; }
        else                 { const int jj = j - 327680;
                               src = Wit + (size_t)jj * 4;
                               dst = 16777216 + 1310720 + (size_t)jj * 4; }
    }
    *(bf16x4*)(ws + dst) = cvt4(*(const f32x4*)src);
}

// ===================== R5 main: fully async fused GEMM =====================
// Tile BM=128 x BN=64, 2 outputs (P,Q), BK=64, 16 K-steps (Q only kt<8).
// 512 thr = 8 waves 2(M) x 4(N); wave tile 64x16/output; acc 32 f32.
// LDS: sA dbuf 2x16K + sB dbuf 2x16K = 64 KiB -> 2 blocks/CU.
__global__ __launch_bounds__(512, 4)
void petnn_fused2(const __bf16* __restrict__ Xb, const __bf16* __restrict__ Sb,
                  const __bf16* __restrict__ wb,
                  const float* __restrict__ bzw, const float* __restrict__ bh,
                  const float* __restrict__ bzc, const float* __restrict__ bit_,
                  float* __restrict__ out)
{
    __shared__ __align__(16) __bf16 sA[2 * 128 * 64];
    __shared__ __align__(16) __bf16 sB[2 * 2 * 64 * 64];

    const int tid = threadIdx.x;
    const int bid = blockIdx.x;
    // XCD-chunked swizzle (2048 wgs, bijective; HW XCD = bid & 7), fam-minor
    // then nblk then mblk: one mblk's 16 sibling blocks co-resident per XCD.
    const int orig = (bid & 7) * 256 + (bid >> 3);
    const int fam  = orig & 1;
    const int nblk = (orig >> 1) & 7;
    const int mblk = orig >> 4;

    const int lane = tid & 63, wid = tid >> 6;
    const int wm = wid >> 2;             // 0..1
    const int wn = wid & 3;              // 0..3

    const int arow0 = mblk * 128;
    const int ncol0 = nblk * 64;

    // A source (glds, swizzle in global addr): thread t, half g in {0,1}:
    // LDS elem g*4096 + t*8  <=> row r = g*64 + (t>>3), chunk c = t&7;
    // source k-chunk = c ^ (r&7).
    const int ar   = tid >> 3;
    const int aswz = ((tid & 7) ^ (ar & 7)) << 3;
    const __bf16* pXA = Xb + (size_t)(arow0 + ar) * 512 + aswz;
    const __bf16* pSA = Sb + (size_t)(arow0 + ar) * 512 + aswz;

    // B sources
    const int bn  = tid >> 3;
    const int bks = ((tid & 7) ^ (bn & 7)) << 3;
    const __bf16* wP = wb + (size_t)fam * 786432 + (size_t)(ncol0 + bn) * 1024 + bks;
    const __bf16* wQ = wb + (size_t)fam * 786432 + 524288
                          + (size_t)(ncol0 + bn) * 512 + bks;

    __bf16* dA = sA + tid * 8;
    __bf16* dB = sB + tid * 8;

    f32x4 aP[4] = {}, aQ[4] = {};

    // prologue: tiles 0 and 1 (4 loads each; vmcnt order = issue order)
    {
        glds16(pXA, dA);                 glds16(pXA + 64 * 512, dA + 4096);
        glds16(wP,  dB);                 glds16(wQ,  dB + 4096);
        glds16(pXA + 64, dA + 8192);     glds16(pXA + 64 * 512 + 64, dA + 8192 + 4096);
        glds16(wP + 64, dB + 8192);      glds16(wQ + 64, dB + 8192 + 4096);
    }

#define MFMA_PHASE(KT, FULL_)                                                  \
    {                                                                          \
        const __bf16* aB = sA + ((KT) & 1) * 8192;                             \
        const __bf16* bB = sB + ((KT) & 1) * 8192;                             \
        _Pragma("unroll")                                                      \
        for (int kk = 0; kk < 2; ++kk) {                                       \
            const int kbe = kk * 32 + (lane >> 4) * 8;                         \
            bf16x8 af[4];                                                      \
            _Pragma("unroll")                                                  \
            for (int mf = 0; mf < 4; ++mf) {                                   \
                const int r = wm * 64 + mf * 16 + (lane & 15);                 \
                af[mf] = *(const bf16x8*)(aB + r * 64 + (kbe ^ ((r & 7) * 8)));\
            }                                                                  \
            const int nr = wn * 16 + (lane & 15);                              \
            const int sx = nr * 64 + (kbe ^ ((nr & 7) * 8));                   \
            const bf16x8 bP = *(const bf16x8*)(bB + sx);                       \
            _Pragma("unroll")                                                  \
            for (int mf = 0; mf < 4; ++mf)                                     \
                aP[mf] = __builtin_amdgcn_mfma_f32_16x16x32_bf16(af[mf], bP, aP[mf], 0, 0, 0); \
            if (FULL_) {                                                       \
                const bf16x8 bQ = *(const bf16x8*)(bB + 4096 + sx);            \
                _Pragma("unroll")                                              \
                for (int mf = 0; mf < 4; ++mf)                                 \
                    aQ[mf] = __builtin_amdgcn_mfma_f32_16x16x32_bf16(af[mf], bQ, aQ[mf], 0, 0, 0); \
            }                                                                  \
        }                                                                      \
    }

// ISS: 0 = none, 1 = A+P, 2 = A+P+Q (loads for tile KT+2)
#define STEP(KT, WAIT, FULL_, ISS)                                             \
    {                                                                          \
        waitvm<WAIT>();                                                        \
        __builtin_amdgcn_sched_barrier(0);                                     \
        __builtin_amdgcn_s_barrier();                                          \
        asm volatile("" ::: "memory");                                         \
        MFMA_PHASE(KT, FULL_)                                                  \
        asm volatile("" ::: "memory");                                         \
        __builtin_amdgcn_sched_barrier(0);                                     \
        __builtin_amdgcn_s_barrier();                                          \
        asm volatile("" ::: "memory");                                         \
        if (ISS) {                                                             \
            const int ktn = (KT) + 2;                                          \
            const __bf16* ab = (ktn < 8) ? pXA : pSA;                          \
            const int kga = (ktn & 7) * 64;                                    \
            glds16(ab + kga, dA + (ktn & 1) * 8192);                           \
            glds16(ab + 64 * 512 + kga, dA + (ktn & 1) * 8192 + 4096);         \
            glds16(wP + ktn * 64, dB + (ktn & 1) * 8192);                      \
            if ((ISS) == 2) glds16(wQ + ktn * 64, dB + (ktn & 1) * 8192 + 4096); \
        }                                                                      \
    }

    STEP(0, 4, true, 2)  STEP(1, 4, true, 2)  STEP(2, 4, true, 2)
    STEP(3, 4, true, 2)  STEP(4, 4, true, 2)  STEP(5, 4, true, 2)
    STEP(6, 4, true, 1)   // issues tile 8 (A+P only)
    STEP(7, 3, true, 1)   // issues tile 9
    STEP(8, 3, false, 1)  STEP(9, 3, false, 1)  STEP(10, 3, false, 1)
    STEP(11, 3, false, 1) STEP(12, 3, false, 1) STEP(13, 3, false, 1)
    STEP(14, 3, false, 0)
    STEP(15, 0, false, 0)

#undef STEP
#undef MFMA_PHASE

    // ---- fused epilogue ----
    // C/D frag layout (m89/m91): col = lane&15, row = (lane>>4)*4 + reg
    const int col  = ncol0 + wn * 16 + (lane & 15);
    const int rowb = arow0 + wm * 64;
    if (fam == 0) {
        const float vzw = bzw[col], vh = bh[col];
        #pragma unroll
        for (int mf = 0; mf < 4; ++mf) {
            #pragma unroll
            for (int j = 0; j < 4; ++j) {
                const int row = rowb + mf * 16 + ((lane >> 4) << 2) + j;
                const size_t off = (size_t)row * DDIM + col;
                const float zw = sigf(aP[mf][j] + vzw);
                const float hh = sigf(aQ[mf][j] + vh);
                const float sv = (float)Sb[off], xv = (float)Xb[off];
                out[off] = sigf((1.0f - zw) * sv + zw * hh + xv);   // S_new
            }
        }
    } else {
        const float vzc = bzc[col], vit = bit_[col];
        #pragma unroll
        for (int mf = 0; mf < 4; ++mf) {
            #pragma unroll
            for (int j = 0; j < 4; ++j) {
                const int row = rowb + mf * 16 + ((lane >> 4) << 2) + j;
                const size_t off = (size_t)row * DDIM + col;
                out[(size_t)BROWS * DDIM + off] =
                    (aP[mf][j] + vzc) + (aQ[mf][j] + vit);          // C_new
            }
        }
    }
}

// ===================== R4 fallback (ws too small) =====================
__global__ __launch_bounds__(256)
void petnn_cvtw(const float* __restrict__ Wzw, const float* __restrict__ Wh,
                const float* __restrict__ Wzc, const float* __restrict__ Wit,
                __bf16* __restrict__ wb)
{
    const int i = blockIdx.x * 256 + threadIdx.x;
    const float* src; size_t dst;
    if (i < 131072)      { src = Wzw + (size_t)i * 4;  dst = (size_t)i * 4; }
    else if (i < 196608) { const int j = i - 131072;
                           src = Wh + (size_t)(j >> 7) * 1024 + (j & 127) * 4;
                           dst = 524288 + (size_t)j * 4; }
    else if (i < 327680) { const int j = i - 196608;
                           src = Wzc + (size_t)j * 4;  dst = 786432 + (size_t)j * 4; }
    else                 { const int j = i - 327680;
                           src = Wit + (size_t)j * 4;  dst = 1310720 + (size_t)j * 4; }
    *(bf16x4*)(wb + dst) = cvt4(*(const f32x4*)src);
}

__global__ __launch_bounds__(512, 4)
void petnn_fused(const float* __restrict__ X,   const float* __restrict__ S,
                 const __bf16* __restrict__ wb,
                 const float* __restrict__ bzw, const float* __restrict__ bh,
                 const float* __restrict__ bzc, const float* __restrict__ bit_,
                 float* __restrict__ out)
{
    __shared__ __align__(16) __bf16 sA[128 * 64];
    __shared__ __align__(16) __bf16 sB[2 * 2 * 64 * 64];

    const int tid = threadIdx.x;
    const int bid = blockIdx.x;
    const int orig = (bid & 7) * 256 + (bid >> 3);
    const int fam  = orig & 1;
    const int nblk = (orig >> 1) & 7;
    const int mblk = orig >> 4;
    const int lane = tid & 63, wid = tid >> 6;
    const int wm = wid >> 2, wn = wid & 3;
    const int arow0 = mblk * 128, ncol0 = nblk * 64;
    const int srow = tid >> 4, skq = (tid & 15) << 2;
    const int bn = tid >> 3;
    const int bks = ((tid & 7) ^ (bn & 7)) << 3;
    const __bf16* wP = wb + (size_t)fam * 786432 + (size_t)(ncol0 + bn) * 1024 + bks;
    const __bf16* wQ = wb + (size_t)fam * 786432 + 524288 + (size_t)(ncol0 + bn) * 512 + bks;
    __bf16* ldsB = sB + tid * 8;

    f32x4 aP[4] = {}, aQ[4] = {};
    f32x4 ra[4];

    glds16(wP, ldsB);
    glds16(wQ, ldsB + 4096);
    #pragma unroll
    for (int p = 0; p < 4; ++p)
        ra[p] = *(const f32x4*)(X + (size_t)(arow0 + p * 32 + srow) * DDIM + skq);
    glds16(wP + 64, ldsB + 8192);
    glds16(wQ + 64, ldsB + 8192 + 4096);

    for (int kt = 0; kt < 16; ++kt) {
        const bool full = kt < 8;
        #pragma unroll
        for (int p = 0; p < 4; ++p) {
            const int r = p * 32 + srow;
            *(bf16x4*)(sA + r * 64 + (skq ^ ((r & 7) * 8))) = cvt4(ra[p]);
        }
        if (kt + 1 < 16) {
            const float* asrc = (kt + 1 < 8) ? X : S;
            const int kga = ((kt + 1) & 7) * 64 + skq;
            #pragma unroll
            for (int p = 0; p < 4; ++p)
                ra[p] = *(const f32x4*)(asrc + (size_t)(arow0 + p * 32 + srow) * DDIM + kga);
        }
        asm volatile("s_waitcnt lgkmcnt(0)" ::: "memory");
        __builtin_amdgcn_s_barrier();

        const __bf16* bb = sB + (kt & 1) * 8192;
        #pragma unroll
        for (int kk = 0; kk < 2; ++kk) {
            const int kbe = kk * 32 + (lane >> 4) * 8;
            bf16x8 af[4];
            #pragma unroll
            for (int mf = 0; mf < 4; ++mf) {
                const int r = wm * 64 + mf * 16 + (lane & 15);
                af[mf] = *(const bf16x8*)(sA + r * 64 + (kbe ^ ((r & 7) * 8)));
            }
            const int nr = wn * 16 + (lane & 15);
            const int sx = nr * 64 + (kbe ^ ((nr & 7) * 8));
            const bf16x8 bP = *(const bf16x8*)(bb + sx);
            #pragma unroll
            for (int mf = 0; mf < 4; ++mf)
                aP[mf] = __builtin_amdgcn_mfma_f32_16x16x32_bf16(af[mf], bP, aP[mf], 0, 0, 0);
            if (full) {
                const bf16x8 bQ = *(const bf16x8*)(bb + 4096 + sx);
                #pragma unroll
                for (int mf = 0; mf < 4; ++mf)
                    aQ[mf] = __builtin_amdgcn_mfma_f32_16x16x32_bf16(af[mf], bQ, aQ[mf], 0, 0, 0);
            }
        }

        if (kt + 1 < 16) {
            asm volatile("" ::: "memory");
            __builtin_amdgcn_s_barrier();
            asm volatile("" ::: "memory");
            if (kt + 2 < 16) {
                __bf16* bd = sB + (kt & 1) * 8192 + tid * 8;
                glds16(wP + (size_t)(kt + 2) * 64, bd);
                if (kt + 2 < 8) glds16(wQ + (size_t)(kt + 2) * 64, bd + 4096);
            }
        }
    }

    const int col  = ncol0 + wn * 16 + (lane & 15);
    const int rowb = arow0 + wm * 64;
    if (fam == 0) {
        const float vzw = bzw[col], vh = bh[col];
        #pragma unroll
        for (int mf = 0; mf < 4; ++mf) {
            #pragma unroll
            for (int j = 0; j < 4; ++j) {
                const int row = rowb + mf * 16 + ((lane >> 4) << 2) + j;
                const size_t off = (size_t)row * DDIM + col;
                const float zw = sigf(aP[mf][j] + vzw);
                const float hh = sigf(aQ[mf][j] + vh);
                out[off] = sigf((1.0f - zw) * S[off] + zw * hh + X[off]);
            }
        }
    } else {
        const float vzc = bzc[col], vit = bit_[col];
        #pragma unroll
        for (int mf = 0; mf < 4; ++mf) {
            #pragma unroll
            for (int j = 0; j < 4; ++j) {
                const int row = rowb + mf * 16 + ((lane >> 4) << 2) + j;
                const size_t off = (size_t)row * DDIM + col;
                out[(size_t)BROWS * DDIM + off] =
                    (aP[mf][j] + vzc) + (aQ[mf][j] + vit);
            }
        }
    }
}

__global__ void petnn_zeroT(float* __restrict__ t) {
    t[blockIdx.x * 256 + threadIdx.x] = 0.0f;   // T_t == 0 exactly
}

extern "C" void kernel_launch(void* const* d_in, const int* in_sizes, int n_in,
                              void* d_out, int out_size, void* d_ws, size_t ws_size,
                              hipStream_t stream) {
    (void)in_sizes; (void)n_in; (void)out_size;
    const float* X    = (const float*)d_in[0];
    const float* S    = (const float*)d_in[1];
    const float* Wzc  = (const float*)d_in[6];
    const float* bzc  = (const float*)d_in[7];
    const float* Wzw  = (const float*)d_in[8];
    const float* bzw  = (const float*)d_in[9];
    const float* Wit  = (const float*)d_in[10];
    const float* bit_ = (const float*)d_in[11];
    const float* Wh   = (const float*)d_in[14];
    const float* bh   = (const float*)d_in[15];
    float* out = (float*)d_out;

    if (ws_size >= 36700160u) {
        __bf16* ws = (__bf16*)d_ws;
        const __bf16* Xb = ws;
        const __bf16* Sb = ws + 8388608;
        const __bf16* wb = ws + 16777216;
        petnn_cvt<<<dim3(17920), dim3(256), 0, stream>>>(X, S, Wzw, Wh, Wzc, Wit, ws);
        petnn_fused2<<<dim3(2048), dim3(512), 0, stream>>>(
            Xb, Sb, wb, bzw, bh, bzc, bit_, out);
    } else {
        __bf16* wb = (__bf16*)d_ws;
        petnn_cvtw<<<dim3(1536), dim3(256), 0, stream>>>(Wzw, Wh, Wzc, Wit, wb);
        petnn_fused<<<dim3(2048), dim3(512), 0, stream>>>(
            X, S, wb, bzw, bh, bzc, bit_, out);
    }
    petnn_zeroT<<<dim3(64), dim3(256), 0, stream>>>(out + 2 * (size_t)BROWS * DDIM);
}